// Round 2
// baseline (263.037 us; speedup 1.0000x reference)
//
#include <hip/hip_runtime.h>

typedef __attribute__((ext_vector_type(8))) _Float16 half8;
typedef __attribute__((ext_vector_type(4))) float f32x4;

#define GAS(p) ((const __attribute__((address_space(1))) void*)(p))
#define LAS(p) ((__attribute__((address_space(3))) void*)(p))

// ---------------------------------------------------------------------------
// Merged prepass. Blocks [0,4096): feat (B,F) fp32 -> fp16 A-fragments.
// Blocks [4096,4576): W1 (E,F,H) fp32 -> fp16 B-fragments.
// Fragment = contiguous 1 KB [16 rows][32 k]; 8-elem group (row,k8) at slot
// k8*16+row so consuming lane l reads bytes [16l,16l+16) = A[m=l&15][k=(l>>4)*8+j].
// ---------------------------------------------------------------------------
__global__ __launch_bounds__(256) void cvt_pre(const float* __restrict__ feat,
                                               const float* __restrict__ W1,
                                               _Float16* __restrict__ A16,
                                               _Float16* __restrict__ W1T) {
    if (blockIdx.x < 4096) {
        int gid = blockIdx.x * 256 + threadIdx.x;      // 1,048,576 groups of 8
        int k8   = gid & 3;
        int m    = (gid >> 2) & 15;
        int frag = gid >> 6;                           // [bt(64)][kc(32)][mf(8)]
        int mf = frag & 7;
        int kc = (frag >> 3) & 31;
        int bt = frag >> 8;
        int b  = bt * 128 + mf * 16 + m;
        int f0 = kc * 32 + k8 * 8;
        const float4* src = (const float4*)(feat + (size_t)b * 1024 + f0);
        float4 v0 = src[0], v1 = src[1];
        half8 o;
        o[0] = (_Float16)v0.x; o[1] = (_Float16)v0.y;
        o[2] = (_Float16)v0.z; o[3] = (_Float16)v0.w;
        o[4] = (_Float16)v1.x; o[5] = (_Float16)v1.y;
        o[6] = (_Float16)v1.z; o[7] = (_Float16)v1.w;
        *(half8*)(A16 + ((size_t)frag * 64 + k8 * 16 + m) * 8) = o;
    } else {
        int gid = (blockIdx.x - 4096) * 256 + threadIdx.x;  // 122,880 groups
        int k8   = gid & 3;
        int n    = (gid >> 2) & 15;
        int frag = gid >> 6;                           // [e(30)][kc(32)][nf(2)]
        int nf = frag & 1;
        int kc = (frag >> 1) & 31;
        int e  = frag >> 6;
        int h  = nf * 16 + n;
        int f0 = kc * 32 + k8 * 8;
        const float* src = W1 + ((size_t)e * 1024 + f0) * 32 + h;
        half8 o;
#pragma unroll
        for (int j = 0; j < 8; ++j) o[j] = (_Float16)src[j * 32];
        *(half8*)(W1T + ((size_t)frag * 64 + k8 * 16 + n) * 8) = o;
    }
}

// ---------------------------------------------------------------------------
// Kernel 1: block = (128 b-rows, 3 emotions). Grid 640 (1-D), XCD-affine
// mapping: bid%8 = XCD (HW round-robin), each XCD owns bt in [8*xcd, 8*xcd+8)
// so its 8 A-tiles (2 MB) + W1T (2 MB) stay resident in the 4 MB per-XCD L2.
// GEMM1 fp16 MFMA (BK=64, global_load_lds) -> selu -> GEMM2 (fp32)
// -> +allW+b2 -> signed L1 norm. Per kc-step per wave: 8 ds_read : 12 MFMA.
// ---------------------------------------------------------------------------
__global__ __launch_bounds__(256) void gemm_mlp(
    const _Float16* __restrict__ A16, const _Float16* __restrict__ W1T,
    const float* __restrict__ b1, const float* __restrict__ W2,
    const float* __restrict__ b2, const float* __restrict__ wts,
    float* __restrict__ wbuf) {
    __shared__ __align__(16) unsigned char smem[33600];
    unsigned char* Ash = smem;                        // 16 KB stage (K-loop)
    unsigned char* Bsh = smem + 16384;                // 12 KB stage (K-loop)
    float* w2s = (float*)(smem + 28672);              // [eo][sub][h][6] = 1152 f
    float* cb2 = (float*)(smem + 33280);              // 36 floats
    float* ews = cb2 + 36;                            // 36 floats
    float* h_sh = (float*)smem;                       // 128*34*4 B (post-loop)

    const int tid = threadIdx.x;
    const int bid = blockIdx.x;      // 640 = 8 xcd * 8 bt * 10 egroups
    const int v   = bid >> 3;
    const int bt  = ((bid & 7) << 3) | (v & 7);       // XCD-affine bt 0..63
    const int e0  = (v >> 3) * 3;                     // emotion triple 0..9
    const int w  = tid >> 6, l = tid & 63;
    const int q  = l >> 4, lc = l & 15;

    for (int i = tid; i < 1152; i += 256) {
        int eo = i / 384, rr = i - eo * 384;          // rr = h*12 + n
        int h  = rr / 12, n = rr - h * 12;
        int sb = n / 6,  j = n - sb * 6;
        w2s[eo * 384 + sb * 192 + h * 6 + j] = W2[e0 * 384 + i];
    }
    if (tid < 36) {
        cb2[tid] = b2[e0 * 12 + tid];
        ews[tid] = __expf(wts[e0 * 12 + tid]);
    }

    const _Float16* Abase = A16 + (size_t)bt * 131072;
    const _Float16* Bbase = W1T + (size_t)e0 * 32768;

    f32x4 zero = {0.f, 0.f, 0.f, 0.f};
    f32x4 acc[2][6];                 // [mf][(be<<1)|nf]
#pragma unroll
    for (int i = 0; i < 2; ++i)
#pragma unroll
        for (int j = 0; j < 6; ++j) acc[i][j] = zero;

    for (int it = 0; it < 16; ++it) {
        const _Float16* Ait = Abase + it * 8192;   // 16 KB (kc = 2it, 2it+1)
#pragma unroll
        for (int i = 0; i < 4; ++i) {
            int s = w * 4 + i;
            __builtin_amdgcn_global_load_lds(GAS(Ait + s * 512 + l * 8),
                                             LAS(Ash + s * 1024), 16, 0, 0);
        }
#pragma unroll
        for (int j = 0; j < 3; ++j) {
            int f  = w * 3 + j;                    // 12 B-frags: [be(3)][kc2(2)][nf(2)]
            int be = f >> 2, kn = f & 3;
            __builtin_amdgcn_global_load_lds(
                GAS(Bbase + be * 32768 + it * 2048 + kn * 512 + l * 8),
                LAS(Bsh + f * 1024), 16, 0, 0);
        }
        __syncthreads();
#pragma unroll
        for (int kc2 = 0; kc2 < 2; ++kc2) {
            half8 a0 = *(half8*)(Ash + (kc2 * 8 + 2 * w + 0) * 1024 + l * 16);
            half8 a1 = *(half8*)(Ash + (kc2 * 8 + 2 * w + 1) * 1024 + l * 16);
            half8 bfr[6];
#pragma unroll
            for (int be = 0; be < 3; ++be)
#pragma unroll
                for (int nf = 0; nf < 2; ++nf)
                    bfr[be * 2 + nf] =
                        *(half8*)(Bsh + (be * 4 + kc2 * 2 + nf) * 1024 + l * 16);
#pragma unroll
            for (int j = 0; j < 6; ++j)
                acc[0][j] = __builtin_amdgcn_mfma_f32_16x16x32_f16(a0, bfr[j], acc[0][j], 0, 0, 0);
#pragma unroll
            for (int j = 0; j < 6; ++j)
                acc[1][j] = __builtin_amdgcn_mfma_f32_16x16x32_f16(a1, bfr[j], acc[1][j], 0, 0, 0);
        }
        __syncthreads();
    }

    const float SC = 1.0507009873554805f, AL = 1.6732632423543772f;
    const int m2 = tid >> 1, sub = tid & 1;

#pragma unroll
    for (int eo = 0; eo < 3; ++eo) {
        // bias + selu -> h_sh[128][34] (stride 34: float2 reads, 2-way=free)
        const float b1a = b1[(e0 + eo) * 32 + lc];
        const float b1b = b1[(e0 + eo) * 32 + 16 + lc];
#pragma unroll
        for (int mf = 0; mf < 2; ++mf)
#pragma unroll
            for (int nf = 0; nf < 2; ++nf)
#pragma unroll
                for (int r = 0; r < 4; ++r) {
                    int m   = w * 32 + mf * 16 + q * 4 + r;  // row=(l>>4)*4+r
                    int col = nf * 16 + lc;                  // col=l&15
                    float x = acc[mf][eo * 2 + nf][r] + (nf ? b1b : b1a);
                    float hv = x > 0.f ? SC * x : SC * AL * (__expf(x) - 1.f);
                    h_sh[m * 34 + col] = hv;
                }
        __syncthreads();

        // GEMM2 + normalize: 2 threads per row, 6 outputs each
        float u[6] = {0.f, 0.f, 0.f, 0.f, 0.f, 0.f};
        const float2* hrow = (const float2*)(h_sh + m2 * 34);
        const float* wbase = w2s + eo * 384 + sub * 192;     // [h][6] runs, 16B-aligned
#pragma unroll
        for (int hp = 0; hp < 16; ++hp) {
            float2 hv = hrow[hp];
            const float* w0 = wbase + hp * 12;
#pragma unroll
            for (int j = 0; j < 6; ++j) u[j] += hv.x * w0[j];
#pragma unroll
            for (int j = 0; j < 6; ++j) u[j] += hv.y * w0[6 + j];
        }
        float sew = 0.f;
#pragma unroll
        for (int i = 0; i < 12; ++i) sew += ews[eo * 12 + i];
        sew = fmaxf(sew, 1e-12f);
        float sabs = 0.f;
#pragma unroll
        for (int j = 0; j < 6; ++j) {
            u[j] += cb2[eo * 12 + sub * 6 + j] + ews[eo * 12 + sub * 6 + j] / sew;
            sabs += fabsf(u[j]);
        }
        sabs += __shfl_xor(sabs, 1);
        float inv = 1.f / fmaxf(sabs, 1e-12f);
        int b = bt * 128 + m2;
        float* dst = wbuf + (size_t)(e0 + eo) * 98304 + b * 12 + sub * 6;
#pragma unroll
        for (int j = 0; j < 6; ++j) dst[j] = u[j] * inv;
        __syncthreads();   // protect h_sh before next eo overwrites
    }
}

// ---------------------------------------------------------------------------
// Kernel 2: mixed = w . dist, softmax over L. 8 rows/block; dist register-
// cached. No max pass: sum|w|=1 and dist in [0,1) => |mixed| < 1, exp safe.
// ---------------------------------------------------------------------------
__global__ __launch_bounds__(256) void mix_softmax(
    const float* __restrict__ dist, const float* __restrict__ wbuf,
    float* __restrict__ out) {
    __shared__ float wsm[8 * 360];                    // [m][e][n]
    const int tid = threadIdx.x;
    const int b0 = blockIdx.x * 8;
    for (int i = tid; i < 2880; i += 256) {
        int e = i / 96, r = i - e * 96;               // r = m*12+n
        wsm[(r / 12) * 360 + e * 12 + (r % 12)] = wbuf[(size_t)e * 98304 + b0 * 12 + r];
    }
    __syncthreads();
    const int m = tid >> 5, l4 = tid & 31;
    const int b = b0 + m;
    const float* dbase = dist + (size_t)b * 1536 + l4 * 4;
    f32x4 d[12];
#pragma unroll
    for (int n = 0; n < 12; ++n) d[n] = *(const f32x4*)(dbase + n * 128);
    const float* wrow = wsm + m * 360;
    for (int e = 0; e < 30; ++e) {
        const float* wr = wrow + e * 12;
        f32x4 a = {0.f, 0.f, 0.f, 0.f};
#pragma unroll
        for (int n = 0; n < 12; ++n) a += wr[n] * d[n];
        f32x4 ex;
        ex[0] = __expf(a[0]); ex[1] = __expf(a[1]);
        ex[2] = __expf(a[2]); ex[3] = __expf(a[3]);
        float sm = ex[0] + ex[1] + ex[2] + ex[3];
#pragma unroll
        for (int s = 16; s >= 1; s >>= 1) sm += __shfl_xor(sm, s);
        f32x4 o = ex * (1.f / sm);
        *(f32x4*)(out + ((size_t)e * 8192 + b) * 128 + l4 * 4) = o;
    }
}

// ---------------------------------------------------------------------------
extern "C" void kernel_launch(void* const* d_in, const int* in_sizes, int n_in,
                              void* d_out, int out_size, void* d_ws, size_t ws_size,
                              hipStream_t stream) {
    const float* dist = (const float*)d_in[0];   // (B, NB, L)
    const float* feat = (const float*)d_in[1];   // (B, F)
    const float* wts  = (const float*)d_in[2];   // (E,1,NB,1)
    const float* W1   = (const float*)d_in[3];   // (E, F, H)
    const float* b1   = (const float*)d_in[4];   // (E, H)
    const float* W2   = (const float*)d_in[5];   // (E, H, NB)
    const float* b2   = (const float*)d_in[6];   // (E, NB)
    float* out = (float*)d_out;                  // (E, B, L)

    _Float16* A16 = (_Float16*)d_ws;                            // 16,777,216 B
    _Float16* W1T = (_Float16*)((char*)d_ws + 16777216);        //  1,966,080 B
    float*   wbuf = (float*)((char*)d_ws + 16777216 + 1966080); // 11,796,480 B (E,B,NB)

    cvt_pre<<<4576, 256, 0, stream>>>(feat, W1, A16, W1T);
    gemm_mlp<<<640, 256, 0, stream>>>(A16, W1T, b1, W2, b2, wts, wbuf);
    mix_softmax<<<1024, 256, 0, stream>>>(dist, wbuf, out);
}

// Round 3
// 251.762 us; speedup vs baseline: 1.0448x; 1.0448x over previous
//
#include <hip/hip_runtime.h>

typedef __attribute__((ext_vector_type(8))) _Float16 half8;
typedef __attribute__((ext_vector_type(4))) float f32x4;

#define GAS(p) ((const __attribute__((address_space(1))) void*)(p))
#define LAS(p) ((__attribute__((address_space(3))) void*)(p))

// ---------------------------------------------------------------------------
// Merged prepass. Blocks [0,4096): feat (B,F) fp32 -> fp16 A-fragments.
// Blocks [4096,4576): W1 (E,F,H) fp32 -> fp16 B-fragments.
// Fragment = contiguous 1 KB [16 rows][32 k]; 8-elem group (row,k8) at slot
// k8*16+row so consuming lane l reads bytes [16l,16l+16) = A[m=l&15][k=(l>>4)*8+j].
// ---------------------------------------------------------------------------
__global__ __launch_bounds__(256) void cvt_pre(const float* __restrict__ feat,
                                               const float* __restrict__ W1,
                                               _Float16* __restrict__ A16,
                                               _Float16* __restrict__ W1T) {
    if (blockIdx.x < 4096) {
        int gid = blockIdx.x * 256 + threadIdx.x;      // 1,048,576 groups of 8
        int k8   = gid & 3;
        int m    = (gid >> 2) & 15;
        int frag = gid >> 6;                           // [bt(64)][kc(32)][mf(8)]
        int mf = frag & 7;
        int kc = (frag >> 3) & 31;
        int bt = frag >> 8;
        int b  = bt * 128 + mf * 16 + m;
        int f0 = kc * 32 + k8 * 8;
        const float4* src = (const float4*)(feat + (size_t)b * 1024 + f0);
        float4 v0 = src[0], v1 = src[1];
        half8 o;
        o[0] = (_Float16)v0.x; o[1] = (_Float16)v0.y;
        o[2] = (_Float16)v0.z; o[3] = (_Float16)v0.w;
        o[4] = (_Float16)v1.x; o[5] = (_Float16)v1.y;
        o[6] = (_Float16)v1.z; o[7] = (_Float16)v1.w;
        *(half8*)(A16 + ((size_t)frag * 64 + k8 * 16 + m) * 8) = o;
    } else {
        int gid = (blockIdx.x - 4096) * 256 + threadIdx.x;  // 122,880 groups
        int k8   = gid & 3;
        int n    = (gid >> 2) & 15;
        int frag = gid >> 6;                           // [e(30)][kc(32)][nf(2)]
        int nf = frag & 1;
        int kc = (frag >> 1) & 31;
        int e  = frag >> 6;
        int h  = nf * 16 + n;
        int f0 = kc * 32 + k8 * 8;
        const float* src = W1 + ((size_t)e * 1024 + f0) * 32 + h;
        half8 o;
#pragma unroll
        for (int j = 0; j < 8; ++j) o[j] = (_Float16)src[j * 32];
        *(half8*)(W1T + ((size_t)frag * 64 + k8 * 16 + n) * 8) = o;
    }
}

// ---------------------------------------------------------------------------
// Kernel 1: block = (128 b-rows, 2 emotions) — round-0 proven geometry.
// CHANGE vs round-0: K-loop is now double-buffered with counted vmcnt +
// raw s_barrier (T3-lite). STAGE(it+1) issues 6 global_load_lds, then
// s_waitcnt vmcnt(6) drains only the OLDEST 6 (= tile it's loads), so tile
// it+1's HBM/L2 latency hides under tile it's MFMA. No vmcnt(0) drain in
// the steady-state loop. LDS 52.4 KB -> 3 blocks/CU.
// ---------------------------------------------------------------------------
__global__ __launch_bounds__(256) void gemm_mlp(
    const _Float16* __restrict__ A16, const _Float16* __restrict__ W1T,
    const float* __restrict__ b1, const float* __restrict__ W2,
    const float* __restrict__ b2, const float* __restrict__ wts,
    float* __restrict__ wbuf) {
    __shared__ __align__(16) unsigned char smem[52416];
    // buf0: A [0,16384) B [16384,24576); buf1: A [24576,40960) B [40960,49152)
    float* w2s = (float*)(smem + 49152);              // 768 floats (2 e)
    float* cb2 = (float*)(smem + 52224);              // 24 floats
    float* ews = cb2 + 24;                            // 24 floats
    float* h_sh = (float*)smem;                       // 128*33*4 B (post-loop)

    const int tid = threadIdx.x;
    const int e0 = blockIdx.x * 2;   // emotion pair 0..14
    const int bt = blockIdx.y;       // 0..63
    const int w  = tid >> 6, l = tid & 63;
    const int q  = l >> 4, lc = l & 15;

    for (int i = tid; i < 768; i += 256) w2s[i] = W2[e0 * 384 + i];
    if (tid < 24) {
        cb2[tid] = b2[e0 * 12 + tid];
        ews[tid] = __expf(wts[e0 * 12 + tid]);
    }

    const _Float16* Abase = A16 + (size_t)bt * 131072;
    const _Float16* Bbase = W1T + (size_t)e0 * 32768;

    f32x4 zero = {0.f, 0.f, 0.f, 0.f};
    f32x4 acc[2][4];                 // [mf][(be<<1)|nf]
#pragma unroll
    for (int i = 0; i < 2; ++i)
#pragma unroll
        for (int j = 0; j < 4; ++j) acc[i][j] = zero;

    // ---- staging helper: 6 global_load_lds per thread (4 A + 2 B) ----
    auto stage = [&](int buf, int it) {
        const _Float16* Ait = Abase + it * 8192;      // 16 KB (kc = 2it, 2it+1)
        unsigned char* Ad = smem + buf * 24576;
        unsigned char* Bd = Ad + 16384;
#pragma unroll
        for (int i = 0; i < 4; ++i) {
            int s = w * 4 + i;
            __builtin_amdgcn_global_load_lds(GAS(Ait + s * 512 + l * 8),
                                             LAS(Ad + s * 1024), 16, 0, 0);
        }
#pragma unroll
        for (int j = 0; j < 2; ++j) {
            int f  = w * 2 + j;                       // 8 B-frags: [be(2)][kc2(2)][nf(2)]
            int be = f >> 2, kn = f & 3;
            __builtin_amdgcn_global_load_lds(
                GAS(Bbase + be * 32768 + it * 2048 + kn * 512 + l * 8),
                LAS(Bd + f * 1024), 16, 0, 0);
        }
    };

    auto compute = [&](int buf) {
        unsigned char* Ad = smem + buf * 24576;
        unsigned char* Bd = Ad + 16384;
#pragma unroll
        for (int kc2 = 0; kc2 < 2; ++kc2) {
            half8 a0  = *(half8*)(Ad + (kc2 * 8 + 2 * w + 0) * 1024 + l * 16);
            half8 a1  = *(half8*)(Ad + (kc2 * 8 + 2 * w + 1) * 1024 + l * 16);
            half8 b00 = *(half8*)(Bd + (0 + kc2 * 2 + 0) * 1024 + l * 16);
            half8 b01 = *(half8*)(Bd + (0 + kc2 * 2 + 1) * 1024 + l * 16);
            half8 b10 = *(half8*)(Bd + (4 + kc2 * 2 + 0) * 1024 + l * 16);
            half8 b11 = *(half8*)(Bd + (4 + kc2 * 2 + 1) * 1024 + l * 16);
            acc[0][0] = __builtin_amdgcn_mfma_f32_16x16x32_f16(a0, b00, acc[0][0], 0, 0, 0);
            acc[0][1] = __builtin_amdgcn_mfma_f32_16x16x32_f16(a0, b01, acc[0][1], 0, 0, 0);
            acc[0][2] = __builtin_amdgcn_mfma_f32_16x16x32_f16(a0, b10, acc[0][2], 0, 0, 0);
            acc[0][3] = __builtin_amdgcn_mfma_f32_16x16x32_f16(a0, b11, acc[0][3], 0, 0, 0);
            acc[1][0] = __builtin_amdgcn_mfma_f32_16x16x32_f16(a1, b00, acc[1][0], 0, 0, 0);
            acc[1][1] = __builtin_amdgcn_mfma_f32_16x16x32_f16(a1, b01, acc[1][1], 0, 0, 0);
            acc[1][2] = __builtin_amdgcn_mfma_f32_16x16x32_f16(a1, b10, acc[1][2], 0, 0, 0);
            acc[1][3] = __builtin_amdgcn_mfma_f32_16x16x32_f16(a1, b11, acc[1][3], 0, 0, 0);
        }
    };

    // ---- pipelined K-loop: 15 steady iters + peeled last ----
    stage(0, 0);
    for (int it = 0; it < 15; ++it) {
        stage((it + 1) & 1, it + 1);                  // 6 newer loads in flight
        asm volatile("s_waitcnt vmcnt(6)" ::: "memory");  // drain tile-it's 6
        __builtin_amdgcn_s_barrier();
        __builtin_amdgcn_sched_barrier(0);
        compute(it & 1);
        __builtin_amdgcn_sched_barrier(0);
        __builtin_amdgcn_s_barrier();                 // all reads of buf done
    }
    asm volatile("s_waitcnt vmcnt(0)" ::: "memory");
    __builtin_amdgcn_s_barrier();
    __builtin_amdgcn_sched_barrier(0);
    compute(1);                                       // it = 15 -> buf 1

    const float SC = 1.0507009873554805f, AL = 1.6732632423543772f;
    const int m2 = tid >> 1, sub = tid & 1;

#pragma unroll
    for (int eo = 0; eo < 2; ++eo) {
        // bias + selu -> h_sh[128][33]
        const float b1a = b1[(e0 + eo) * 32 + lc];
        const float b1b = b1[(e0 + eo) * 32 + 16 + lc];
#pragma unroll
        for (int mf = 0; mf < 2; ++mf)
#pragma unroll
            for (int nf = 0; nf < 2; ++nf)
#pragma unroll
                for (int r = 0; r < 4; ++r) {
                    int m   = w * 32 + mf * 16 + q * 4 + r;  // row=(l>>4)*4+r
                    int col = nf * 16 + lc;                  // col=l&15
                    float x = acc[mf][eo * 2 + nf][r] + (nf ? b1b : b1a);
                    float hv = x > 0.f ? SC * x : SC * AL * (__expf(x) - 1.f);
                    h_sh[m * 33 + col] = hv;
                }
        __syncthreads();

        // GEMM2 + normalize: 2 threads per row, 6 outputs each
        float u[6] = {0.f, 0.f, 0.f, 0.f, 0.f, 0.f};
        const float* hrow = h_sh + m2 * 33;
        const float* wbase = w2s + eo * 384 + sub * 6;
#pragma unroll 8
        for (int h = 0; h < 32; ++h) {
            float hv = hrow[h];
            const float* wr = wbase + h * 12;
#pragma unroll
            for (int j = 0; j < 6; ++j) u[j] += hv * wr[j];
        }
        float sew = 0.f;
#pragma unroll
        for (int i = 0; i < 12; ++i) sew += ews[eo * 12 + i];
        sew = fmaxf(sew, 1e-12f);
        float sabs = 0.f;
#pragma unroll
        for (int j = 0; j < 6; ++j) {
            u[j] += cb2[eo * 12 + sub * 6 + j] + ews[eo * 12 + sub * 6 + j] / sew;
            sabs += fabsf(u[j]);
        }
        sabs += __shfl_xor(sabs, 1);
        float inv = 1.f / fmaxf(sabs, 1e-12f);
        int b = bt * 128 + m2;
        float* dst = wbuf + (size_t)(e0 + eo) * 98304 + b * 12 + sub * 6;
#pragma unroll
        for (int j = 0; j < 6; ++j) dst[j] = u[j] * inv;
        __syncthreads();   // protect h_sh before next eo overwrites
    }
}

// ---------------------------------------------------------------------------
// Kernel 2: mixed = w . dist, softmax over L. 8 rows/block; dist register-
// cached. No max pass: sum|w|=1 and dist in [0,1) => |mixed| < 1, exp safe.
// ---------------------------------------------------------------------------
__global__ __launch_bounds__(256) void mix_softmax(
    const float* __restrict__ dist, const float* __restrict__ wbuf,
    float* __restrict__ out) {
    __shared__ float wsm[8 * 360];                    // [m][e][n]
    const int tid = threadIdx.x;
    const int b0 = blockIdx.x * 8;
    for (int i = tid; i < 2880; i += 256) {
        int e = i / 96, r = i - e * 96;               // r = m*12+n
        wsm[(r / 12) * 360 + e * 12 + (r % 12)] = wbuf[(size_t)e * 98304 + b0 * 12 + r];
    }
    __syncthreads();
    const int m = tid >> 5, l4 = tid & 31;
    const int b = b0 + m;
    const float* dbase = dist + (size_t)b * 1536 + l4 * 4;
    f32x4 d[12];
#pragma unroll
    for (int n = 0; n < 12; ++n) d[n] = *(const f32x4*)(dbase + n * 128);
    const float* wrow = wsm + m * 360;
    for (int e = 0; e < 30; ++e) {
        const float* wr = wrow + e * 12;
        f32x4 a = {0.f, 0.f, 0.f, 0.f};
#pragma unroll
        for (int n = 0; n < 12; ++n) a += wr[n] * d[n];
        f32x4 ex;
        ex[0] = __expf(a[0]); ex[1] = __expf(a[1]);
        ex[2] = __expf(a[2]); ex[3] = __expf(a[3]);
        float sm = ex[0] + ex[1] + ex[2] + ex[3];
#pragma unroll
        for (int s = 16; s >= 1; s >>= 1) sm += __shfl_xor(sm, s);
        f32x4 o = ex * (1.f / sm);
        *(f32x4*)(out + ((size_t)e * 8192 + b) * 128 + l4 * 4) = o;
    }
}

// ---------------------------------------------------------------------------
extern "C" void kernel_launch(void* const* d_in, const int* in_sizes, int n_in,
                              void* d_out, int out_size, void* d_ws, size_t ws_size,
                              hipStream_t stream) {
    const float* dist = (const float*)d_in[0];   // (B, NB, L)
    const float* feat = (const float*)d_in[1];   // (B, F)
    const float* wts  = (const float*)d_in[2];   // (E,1,NB,1)
    const float* W1   = (const float*)d_in[3];   // (E, F, H)
    const float* b1   = (const float*)d_in[4];   // (E, H)
    const float* W2   = (const float*)d_in[5];   // (E, H, NB)
    const float* b2   = (const float*)d_in[6];   // (E, NB)
    float* out = (float*)d_out;                  // (E, B, L)

    _Float16* A16 = (_Float16*)d_ws;                            // 16,777,216 B
    _Float16* W1T = (_Float16*)((char*)d_ws + 16777216);        //  1,966,080 B
    float*   wbuf = (float*)((char*)d_ws + 16777216 + 1966080); // 11,796,480 B (E,B,NB)

    cvt_pre<<<4576, 256, 0, stream>>>(feat, W1, A16, W1T);
    dim3 g1(15, 64);
    gemm_mlp<<<g1, 256, 0, stream>>>(A16, W1T, b1, W2, b2, wts, wbuf);
    mix_softmax<<<1024, 256, 0, stream>>>(dist, wbuf, out);
}